// Round 4
// baseline (1374.033 us; speedup 1.0000x reference)
//
#include <hip/hip_runtime.h>
#include <hip/hip_bf16.h>
#include <math.h>

#define DIMX 2048
#define SLEN 2048
#define BSZ 2
#define NHEADS 16
#define HDIM 128
#define FFND 8192
#define CTXL 512
#define LN_EPS 1e-6f

typedef __attribute__((ext_vector_type(8))) short short8_t;
typedef __attribute__((ext_vector_type(4))) short short4_t;
typedef __attribute__((ext_vector_type(4))) float f32x4;
typedef __hip_bfloat16 bf16;

__device__ __forceinline__ short f2bf(float f) {
  union { float f; unsigned u; } v; v.f = f;
  return (short)((v.u + 0x7FFFu + ((v.u >> 16) & 1u)) >> 16);
}
__device__ __forceinline__ float bf2f(short s) {
  union { unsigned u; float f; } v; v.u = ((unsigned)(unsigned short)s) << 16;
  return v.f;
}

__device__ __forceinline__ void gload16(const void* g, void* l) {
  __builtin_amdgcn_global_load_lds(
      (const __attribute__((address_space(1))) unsigned int*)g,
      (__attribute__((address_space(3))) unsigned int*)l, 16, 0, 0);
}

__device__ __forceinline__ float wred_sum(float v) {
#pragma unroll
  for (int o = 32; o > 0; o >>= 1) v += __shfl_xor(v, o, 64);
  return v;
}

__global__ void em_kernel(const float* __restrict__ e, const float* __restrict__ mod,
                          float* __restrict__ em, int n) {
  int i = blockIdx.x * 256 + threadIdx.x;
  if (i < n) em[i] = e[i] + mod[i % (6 * DIMX)];
}

__global__ void cvt_kernel(const float* __restrict__ in, bf16* __restrict__ out, int n8) {
  int i = blockIdx.x * 256 + threadIdx.x;
  if (i >= n8) return;
  float4 a = *(const float4*)(in + (size_t)i * 8);
  float4 b = *(const float4*)(in + (size_t)i * 8 + 4);
  float fv[8] = {a.x, a.y, a.z, a.w, b.x, b.y, b.z, b.w};
  short8_t o;
#pragma unroll
  for (int j = 0; j < 8; ++j) o[j] = f2bf(fv[j]);
  *(short8_t*)((short*)out + (size_t)i * 8) = o;
}

__global__ void packb_kernel(const float* b0, const float* b1, const float* b2,
                             float* __restrict__ dst, int n) {
  int i = blockIdx.x * 256 + threadIdx.x;
  if (i >= n) return;
  int seg = i >> 11, j = i & 2047;
  const float* s = seg == 0 ? b0 : (seg == 1 ? b1 : b2);
  dst[i] = s[j];
}

// W fp32 [K][N] -> Wt bf16 [noff+N][K]
__global__ __launch_bounds__(256) void transpose_w(const float* __restrict__ W,
                                                   bf16* __restrict__ Wt, int K, int N,
                                                   int noff) {
  __shared__ short tile[64 * 68];
  int k0 = blockIdx.y << 6, n0 = blockIdx.x << 6;
  int t = threadIdx.x;
#pragma unroll
  for (int p = 0; p < 4; ++p) {
    int lin = p * 1024 + t * 4;
    int kr = lin >> 6, nc = lin & 63;
    float4 f = *(const float4*)(W + (size_t)(k0 + kr) * N + n0 + nc);
    tile[(nc + 0) * 68 + kr] = f2bf(f.x);
    tile[(nc + 1) * 68 + kr] = f2bf(f.y);
    tile[(nc + 2) * 68 + kr] = f2bf(f.z);
    tile[(nc + 3) * 68 + kr] = f2bf(f.w);
  }
  __syncthreads();
#pragma unroll
  for (int p = 0; p < 4; ++p) {
    int lin = p * 1024 + t * 4;
    int nr = lin >> 6, kc = lin & 63;
    short4_t s = *(const short4_t*)&tile[nr * 68 + kc];
    *(short4_t*)((short*)Wt + (size_t)(noff + n0 + nr) * K + k0 + kc) = s;
  }
}

__global__ __launch_bounds__(256) void ln_kernel(
    const float* __restrict__ x, const float* __restrict__ gamma,
    const float* __restrict__ beta, int gbstride, float addone,
    int rows_per_b, bf16* __restrict__ out) {
  int row = blockIdx.x;
  int t = threadIdx.x;
  const float* xr = x + (size_t)row * DIMX;
  float4 v0 = *(const float4*)(xr + t * 8);
  float4 v1 = *(const float4*)(xr + t * 8 + 4);
  float vv[8] = {v0.x, v0.y, v0.z, v0.w, v1.x, v1.y, v1.z, v1.w};
  float s = 0.f, ss = 0.f;
#pragma unroll
  for (int i = 0; i < 8; ++i) { s += vv[i]; ss += vv[i] * vv[i]; }
  __shared__ float red[8];
  s = wred_sum(s); ss = wred_sum(ss);
  int wid = t >> 6;
  if ((t & 63) == 0) { red[wid] = s; red[4 + wid] = ss; }
  __syncthreads();
  float sum = red[0] + red[1] + red[2] + red[3];
  float sumsq = red[4] + red[5] + red[6] + red[7];
  float mean = sum * (1.f / DIMX);
  float var = sumsq * (1.f / DIMX) - mean * mean;
  float rs = rsqrtf(var + LN_EPS);
  int b = row / rows_per_b;
  const float* g = gamma + (size_t)b * gbstride;
  const float* be = beta + (size_t)b * gbstride;
  short8_t o;
#pragma unroll
  for (int i = 0; i < 8; ++i) {
    int d = t * 8 + i;
    float y = (vv[i] - mean) * rs;
    o[i] = f2bf(y * (addone + g[d]) + be[d]);
  }
  *(short8_t*)((short*)out + (size_t)row * DIMX + t * 8) = o;
}

__global__ __launch_bounds__(256) void rms_rope_kernel(
    const bf16* __restrict__ x, int xstride, const float* __restrict__ w,
    const float* __restrict__ fcos, const float* __restrict__ fsin,
    int do_rope, bf16* __restrict__ out) {
  int row = blockIdx.x;
  int t = threadIdx.x;
  short8_t xi = *(const short8_t*)((const short*)x + (size_t)row * xstride + t * 8);
  float vv[8];
#pragma unroll
  for (int i = 0; i < 8; ++i) vv[i] = bf2f(xi[i]);
  float ss = 0.f;
#pragma unroll
  for (int i = 0; i < 8; ++i) ss += vv[i] * vv[i];
  __shared__ float red[4];
  ss = wred_sum(ss);
  int wid = t >> 6;
  if ((t & 63) == 0) red[wid] = ss;
  __syncthreads();
  float sumsq = red[0] + red[1] + red[2] + red[3];
  float rs = rsqrtf(sumsq * (1.f / DIMX) + LN_EPS);
  float y[8];
#pragma unroll
  for (int i = 0; i < 8; ++i) y[i] = vv[i] * rs * w[t * 8 + i];
  if (do_rope) {
    int s = row % SLEN;
    int f = s >> 8, hh = (s >> 4) & 15, ww = s & 15;
    int jb = ((t * 8) % HDIM) >> 1;
#pragma unroll
    for (int p = 0; p < 4; ++p) {
      int j = jb + p;
      int src = (j < 22) ? f : ((j < 43) ? hh : ww);
      float c = fcos[src * 64 + j];
      float sn = fsin[src * 64 + j];
      float xr_ = y[2 * p], xim = y[2 * p + 1];
      y[2 * p] = xr_ * c - xim * sn;
      y[2 * p + 1] = xr_ * sn + xim * c;
    }
  }
  short8_t o;
#pragma unroll
  for (int i = 0; i < 8; ++i) o[i] = f2bf(y[i]);
  *(short8_t*)((short*)out + (size_t)row * DIMX + t * 8) = o;
}

// ---------------- 256x256 8-phase GEMM (T2+T3+T4+T5) -------------------
// C[M][N] = A[M][K] @ Bt[N][K]^T (+bias).  8 waves (2M x 4N), BK=64,
// per-wave out 128x64.  Per K-tile: 4 phases {ds_read quadrant; stage one
// half-tile of a future tile; barrier; setprio; 16 MFMA; setprio; barrier}.
// vmcnt(4) once per tile.  modes: 0 raw fp32 (no bias); 1 bf16; 2 bf16 gelu;
// 3 fp32 resid+v*scale; 4 fp32 resid+(part+v)*scale (split-K combine).
#define RD_A(mh) { _Pragma("unroll") for (int mi = 0; mi < 4; ++mi) { \
    int r = wm * 128 + (mh) * 64 + mi * 16 + l15; int rb = r * 64; int r7 = r & 7; \
    a[mi][0] = *(const short8_t*)&As[buf][rb + ((koff ^ r7) << 3)]; \
    a[mi][1] = *(const short8_t*)&As[buf][rb + (((4 + koff) ^ r7) << 3)]; } }
#define RD_B(nh) { _Pragma("unroll") for (int nj = 0; nj < 2; ++nj) { \
    int r = wn * 64 + (nh) * 32 + nj * 16 + l15; int rb = r * 64; int r7 = r & 7; \
    b[nj][0] = *(const short8_t*)&Bs[buf][rb + ((koff ^ r7) << 3)]; \
    b[nj][1] = *(const short8_t*)&Bs[buf][rb + (((4 + koff) ^ r7) << 3)]; } }
#define MMA(mh, nh) { _Pragma("unroll") for (int kk = 0; kk < 2; ++kk) \
    _Pragma("unroll") for (int mi = 0; mi < 4; ++mi) \
    _Pragma("unroll") for (int nj = 0; nj < 2; ++nj) \
      acc[(mh)*4+mi][(nh)*2+nj] = __builtin_amdgcn_mfma_f32_16x16x32_bf16( \
          a[mi][kk], b[nj][kk], acc[(mh)*4+mi][(nh)*2+nj], 0, 0, 0); }
#define BAR asm volatile("s_barrier" ::: "memory")
#define SETPRIO(x) __builtin_amdgcn_s_setprio(x)

__global__ __launch_bounds__(512) void gemm256(
    const bf16* __restrict__ A, const bf16* __restrict__ Bt,
    const float* __restrict__ bias,
    float* outF, bf16* outB,
    const float* resid, const float* __restrict__ scale, const float* part,
    int scstride, int rows_per_b, int gn, int N, int K, int lda, int ldb,
    int k0, int mode) {
  __shared__ short As[2][16384];
  __shared__ short Bs[2][16384];
  int t = threadIdx.x, lane = t & 63, wv = t >> 6;
  int l15 = lane & 15, koff = lane >> 4;
  int wm = wv >> 2, wn = wv & 3;
  int nwg = gridDim.x, cpx = nwg >> 3;
  int swz = (blockIdx.x & 7) * cpx + (blockIdx.x >> 3);
  int by = swz / gn, bx = swz % gn;
  int m0 = by << 8, n0 = bx << 8;

  f32x4 acc[8][4] = {};
  short8_t a[4][2], b[2][2];

  int srcChunk = ((lane & 7) ^ (lane >> 3)) << 3;  // pre-swizzled 16B chunk
  int rowInSlot = lane >> 3;
  const short* Ap = (const short*)A;
  const short* Bp = (const short*)Bt;

  auto stageA = [&](int bufI, int kkE, int late) {
#pragma unroll
    for (int i = 0; i < 2; ++i) {
      int idx = i * 8 + wv;
      int slot = ((idx >> 3) << 4) + (idx & 7) + (late ? 8 : 0);
      int row = slot * 8 + rowInSlot;
      gload16(Ap + (size_t)(m0 + row) * lda + kkE + srcChunk, &As[bufI][slot << 9]);
    }
  };
  auto stageB = [&](int bufI, int kkE, int late) {
#pragma unroll
    for (int i = 0; i < 2; ++i) {
      int idx = i * 8 + wv;
      int slot = ((idx >> 2) << 3) + (idx & 3) + (late ? 4 : 0);
      int row = slot * 8 + rowInSlot;
      gload16(Bp + (size_t)(n0 + row) * ldb + kkE + srcChunk, &Bs[bufI][slot << 9]);
    }
  };

  int NT = K >> 6;
  // prologue: Ae0 Be0 Al0 Bl0 Ae1 Be1  (12 vmem instr)
  stageA(0, k0, 0); stageB(0, k0, 0);
  stageA(0, k0, 1); stageB(0, k0, 1);
  stageA(1, k0 + 64, 0); stageB(1, k0 + 64, 0);
  asm volatile("s_waitcnt vmcnt(4)" ::: "memory");  // tile0 landed
  BAR;

  for (int tt = 0; tt < NT; ++tt) {
    int buf = tt & 1;
    int kk1 = k0 + (((tt + 1) < NT ? (tt + 1) : 0) << 6);
    int kk2 = k0 + (((tt + 2) < NT ? (tt + 2) : 0) << 6);
    // ph0: quadrant (mh0, nh0); stage A-late(t+1) -> other buf
    RD_A(0); RD_B(0);
    stageA(buf ^ 1, kk1, 1);
    BAR; SETPRIO(1); MMA(0, 0); SETPRIO(0); BAR;
    // ph1: (mh0, nh1); stage B-late(t+1)
    RD_B(1);
    stageB(buf ^ 1, kk1, 1);
    BAR; SETPRIO(1); MMA(0, 1); SETPRIO(0); BAR;
    // ph2: (mh1, nh0); stage A-early(t+2) -> this buf (A-early reads done ph0/1)
    RD_A(1); RD_B(0);
    stageA(buf, kk2, 0);
    BAR; SETPRIO(1); MMA(1, 0); SETPRIO(0); BAR;
    // ph3: (mh1, nh1); stage B-early(t+2) (B-early reads done ph0/2)
    RD_B(1);
    stageB(buf, kk2, 0);
    BAR; SETPRIO(1); MMA(1, 1); SETPRIO(0);
    asm volatile("s_waitcnt vmcnt(4)" ::: "memory");  // tile t+1 fully landed
    BAR;
  }
  asm volatile("s_waitcnt vmcnt(0)" ::: "memory");  // drain tail garbage stages

  int mo = m0 + wm * 128, no = n0 + wn * 64;
#pragma unroll
  for (int mf = 0; mf < 8; ++mf)
#pragma unroll
    for (int nf = 0; nf < 4; ++nf) {
      int n = no + nf * 16 + l15;
      float bia = (mode == 0) ? 0.f : bias[n];
#pragma unroll
      for (int r = 0; r < 4; ++r) {
        int m = mo + mf * 16 + koff * 4 + r;
        float vv = acc[mf][nf][r] + bia;
        size_t idx = (size_t)m * N + n;
        if (mode == 0) {
          outF[idx] = vv;
        } else if (mode == 1) {
          ((short*)outB)[idx] = f2bf(vv);
        } else if (mode == 2) {
          float g = 0.5f * vv * (1.f + tanhf(0.7978845608f * (vv + 0.044715f * vv * vv * vv)));
          ((short*)outB)[idx] = f2bf(g);
        } else if (mode == 3) {
          float sc = scale ? scale[(size_t)(m / rows_per_b) * scstride + n] : 1.0f;
          outF[idx] = resid[idx] + vv * sc;
        } else {
          float sc = scale ? scale[(size_t)(m / rows_per_b) * scstride + n] : 1.0f;
          outF[idx] = resid[idx] + (part[idx] + vv) * sc;
        }
      }
    }
}

// ---------------- 128x128 2-phase GEMM (kept for small-M shapes) --------
__global__ __launch_bounds__(256) void gemm_bt(
    const bf16* __restrict__ A, const bf16* __restrict__ Bt,
    const float* __restrict__ bias,
    float* outF, bf16* outB,
    const float* resid, const float* __restrict__ scale,
    int scstride, int rows_per_b, int gn, int N, int K, int mode) {
  __shared__ short As[2][128 * 64];
  __shared__ short Bs[2][128 * 64];
  int t = threadIdx.x, lane = t & 63, wv = t >> 6;
  int nwg = gridDim.x, cpx = nwg >> 3;
  int swz = (blockIdx.x & 7) * cpx + (blockIdx.x >> 3);
  int by = swz / gn, bx = swz % gn;
  int m0 = by << 7, n0 = bx << 7;
  f32x4 acc[4][4] = {};
  int mo_l = (wv >> 1) << 6, no_l = (wv & 1) << 6;

  int srow[4], scol[4];
#pragma unroll
  for (int j = 0; j < 4; ++j) {
    srow[j] = wv * 32 + j * 8 + (lane >> 3);
    scol[j] = ((lane & 7) ^ (srow[j] & 7)) << 3;
  }
  const short* Ap = (const short*)A;
  const short* Bp = (const short*)Bt;

  int koff = lane >> 4;
  int rowA[4], rowB[4];
#pragma unroll
  for (int i = 0; i < 4; ++i) {
    rowA[i] = mo_l + i * 16 + (lane & 15);
    rowB[i] = no_l + i * 16 + (lane & 15);
  }

  auto stage = [&](int bufI, int kk) {
#pragma unroll
    for (int j = 0; j < 4; ++j) {
      gload16(Ap + (size_t)(m0 + srow[j]) * K + kk + scol[j],
              &As[bufI][(wv * 32 + j * 8) * 64]);
      gload16(Bp + (size_t)(n0 + srow[j]) * K + kk + scol[j],
              &Bs[bufI][(wv * 32 + j * 8) * 64]);
    }
  };

  stage(0, 0);
  __syncthreads();
  int cur = 0;
  for (int kk = 0; kk < K; kk += 64) {
    int nxt = cur ^ 1;
    if (kk + 64 < K) stage(nxt, kk + 64);
    short8_t af[2][4], bfv[2][4];
#pragma unroll
    for (int h = 0; h < 2; ++h)
#pragma unroll
      for (int i = 0; i < 4; ++i) {
        int cA = ((h * 4 + koff) ^ (rowA[i] & 7)) << 3;
        af[h][i] = *(const short8_t*)&As[cur][rowA[i] * 64 + cA];
        int cB = ((h * 4 + koff) ^ (rowB[i] & 7)) << 3;
        bfv[h][i] = *(const short8_t*)&Bs[cur][rowB[i] * 64 + cB];
      }
#pragma unroll
    for (int h = 0; h < 2; ++h)
#pragma unroll
      for (int mt = 0; mt < 4; ++mt)
#pragma unroll
        for (int nt = 0; nt < 4; ++nt)
          acc[mt][nt] = __builtin_amdgcn_mfma_f32_16x16x32_bf16(af[h][mt], bfv[h][nt], acc[mt][nt], 0, 0, 0);
    __syncthreads();
    cur = nxt;
  }

  int mo = m0 + mo_l, no = n0 + no_l;
#pragma unroll
  for (int mt = 0; mt < 4; ++mt)
#pragma unroll
    for (int nt = 0; nt < 4; ++nt) {
      int n = no + nt * 16 + (lane & 15);
      float bia = bias[n];
#pragma unroll
      for (int r = 0; r < 4; ++r) {
        int m = mo + mt * 16 + (lane >> 4) * 4 + r;
        float vv = acc[mt][nt][r] + bia;
        size_t idx = (size_t)m * N + n;
        if (mode == 1) {
          ((short*)outB)[idx] = f2bf(vv);
        } else if (mode == 2) {
          float g = 0.5f * vv * (1.f + tanhf(0.7978845608f * (vv + 0.044715f * vv * vv * vv)));
          ((short*)outB)[idx] = f2bf(g);
        } else {
          float sc = scale ? scale[(size_t)(m / rows_per_b) * scstride + n] : 1.0f;
          outF[idx] = resid[idx] + vv * sc;
        }
      }
    }
}

// Flash attention with strided q/k/v inputs
__global__ __launch_bounds__(256) void attn_kernel(
    const bf16* __restrict__ q, const bf16* __restrict__ k,
    const bf16* __restrict__ v, bf16* __restrict__ y,
    int QL, int KVL, int qs, int ks, int vs, float scl) {
  __shared__ short Kt[64 * 136];
  __shared__ short Vt[128 * 72];
  __shared__ short Pl[4 * 16 * 72];
  __shared__ float rl[4 * 16];
  __shared__ float ll[4 * 16];
  int t = threadIdx.x, lane = t & 63, wv = t >> 6;
  int bh = blockIdx.y;
  int b = bh / NHEADS, h = bh % NHEADS;
  int q0 = blockIdx.x * 64 + wv * 16;
  const short* qp = (const short*)q;
  const short* kp = (const short*)k;
  const short* vp = (const short*)v;
  short8_t qf[4];
  {
    size_t qbase = ((size_t)(b * QL) + q0 + (lane & 15)) * qs + h * HDIM + (lane >> 4) * 8;
#pragma unroll
    for (int kc = 0; kc < 4; ++kc) qf[kc] = *(const short8_t*)(qp + qbase + kc * 32);
  }
  f32x4 o[8] = {};
  float m_run = -1e30f, l_run = 0.f;
  int strow = t >> 2, stcol = (t & 3) * 32;
  for (int kt0 = 0; kt0 < KVL; kt0 += 64) {
    const short* ksrc = kp + ((size_t)(b * KVL + kt0 + strow) * ks + h * HDIM + stcol);
    const short* vsrc = vp + ((size_t)(b * KVL + kt0 + strow) * vs + h * HDIM + stcol);
#pragma unroll
    for (int c = 0; c < 4; ++c)
      *(short8_t*)&Kt[strow * 136 + stcol + c * 8] = *(const short8_t*)(ksrc + c * 8);
#pragma unroll
    for (int c = 0; c < 4; ++c) {
      short8_t vvv = *(const short8_t*)(vsrc + c * 8);
#pragma unroll
      for (int e = 0; e < 8; ++e) Vt[(stcol + c * 8 + e) * 72 + strow] = vvv[e];
    }
    __syncthreads();
    f32x4 st[4];
#pragma unroll
    for (int kt = 0; kt < 4; ++kt) {
      f32x4 aa = {0.f, 0.f, 0.f, 0.f};
#pragma unroll
      for (int kc = 0; kc < 4; ++kc) {
        short8_t kf = *(const short8_t*)&Kt[(kt * 16 + (lane & 15)) * 136 + kc * 32 + (lane >> 4) * 8];
        aa = __builtin_amdgcn_mfma_f32_16x16x32_bf16(kf, qf[kc], aa, 0, 0, 0);
      }
      st[kt] = aa;
    }
    float mt_ = -1e30f;
#pragma unroll
    for (int kt = 0; kt < 4; ++kt)
#pragma unroll
      for (int r = 0; r < 4; ++r) mt_ = fmaxf(mt_, st[kt][r]);
    mt_ = fmaxf(mt_, __shfl_xor(mt_, 16, 64));
    mt_ = fmaxf(mt_, __shfl_xor(mt_, 32, 64));
    mt_ *= scl;
    float m_new = fmaxf(m_run, mt_);
    float rfac = __expf(m_run - m_new);
    float ps = 0.f;
#pragma unroll
    for (int kt = 0; kt < 4; ++kt)
#pragma unroll
      for (int r = 0; r < 4; ++r) {
        float p = __expf(st[kt][r] * scl - m_new);
        st[kt][r] = p;
        ps += p;
      }
    ps += __shfl_xor(ps, 16, 64);
    ps += __shfl_xor(ps, 32, 64);
    l_run = l_run * rfac + ps;
    m_run = m_new;
    if (lane < 16) rl[wv * 16 + lane] = rfac;
#pragma unroll
    for (int kt = 0; kt < 4; ++kt)
#pragma unroll
      for (int r = 0; r < 4; ++r)
        Pl[(wv * 16 + (lane & 15)) * 72 + kt * 16 + (lane >> 4) * 4 + r] = f2bf(st[kt][r]);
    float rr[4];
#pragma unroll
    for (int r = 0; r < 4; ++r) rr[r] = rl[wv * 16 + (lane >> 4) * 4 + r];
#pragma unroll
    for (int dt = 0; dt < 8; ++dt)
#pragma unroll
      for (int r = 0; r < 4; ++r) o[dt][r] *= rr[r];
#pragma unroll
    for (int kc2 = 0; kc2 < 2; ++kc2) {
      short8_t pa = *(const short8_t*)&Pl[(wv * 16 + (lane & 15)) * 72 + kc2 * 32 + (lane >> 4) * 8];
#pragma unroll
      for (int dt = 0; dt < 8; ++dt) {
        short8_t vf = *(const short8_t*)&Vt[(dt * 16 + (lane & 15)) * 72 + kc2 * 32 + (lane >> 4) * 8];
        o[dt] = __builtin_amdgcn_mfma_f32_16x16x32_bf16(pa, vf, o[dt], 0, 0, 0);
      }
    }
    __syncthreads();
  }
  if (lane < 16) ll[wv * 16 + lane] = 1.f / l_run;
  float li[4];
#pragma unroll
  for (int r = 0; r < 4; ++r) li[r] = ll[wv * 16 + (lane >> 4) * 4 + r];
  short* yp = (short*)y;
#pragma unroll
  for (int dt = 0; dt < 8; ++dt)
#pragma unroll
    for (int r = 0; r < 4; ++r) {
      int qq = q0 + (lane >> 4) * 4 + r;
      int d = dt * 16 + (lane & 15);
      yp[((size_t)(b * QL) + qq) * DIMX + h * HDIM + d] = f2bf(o[dt][r] * li[r]);
    }
}

// ws layout (bytes)
#define OFF_EM    0ull
#define OFF_BQKV  (512ull << 10)
#define OFF_BCKV  (560ull << 10)
#define OFF_XN    (1ull << 20)
#define OFF_QKV   (17ull << 20)   // fused qkv out: 48 MB (ends 65)
#define OFF_CAQ   (17ull << 20)
#define OFF_KV    (33ull << 20)
#define OFF_QB    (65ull << 20)
#define OFF_KB    (81ull << 20)
#define OFF_YB    (97ull << 20)
#define OFF_CTX   (113ull << 20)
#define OFF_WBUF  (117ull << 20)  // 32 MB max
#define OFF_HB    (17ull << 20)   // FFN hidden 64 MB (17..81)
#define OFF_P0    (81ull << 20)   // FFN2 split-K partial, fp32 32 MB (81..113)

extern "C" void kernel_launch(void* const* d_in, const int* in_sizes, int n_in,
                              void* d_out, int out_size, void* d_ws, size_t ws_size,
                              hipStream_t stream) {
  const float* x       = (const float*)d_in[0];
  const float* e       = (const float*)d_in[1];
  const float* context = (const float*)d_in[2];
  const float* fcos    = (const float*)d_in[3];
  const float* fsin    = (const float*)d_in[4];
  const float* modu    = (const float*)d_in[5];
  const float* sa_wq = (const float*)d_in[6];  const float* sa_bq = (const float*)d_in[7];
  const float* sa_wk = (const float*)d_in[8];  const float* sa_bk = (const float*)d_in[9];
  const float* sa_wv = (const float*)d_in[10]; const float* sa_bv = (const float*)d_in[11];
  const float* sa_wo = (const float*)d_in[12]; const float* sa_bo = (const float*)d_in[13];
  const float* sa_nq = (const float*)d_in[14]; const float* sa_nk = (const float*)d_in[15];
  const float* ca_wq = (const float*)d_in[16]; const float* ca_bq = (const float*)d_in[17];
  const float* ca_wk = (const float*)d_in[18]; const float* ca_bk = (const float*)d_in[19];
  const float* ca_wv = (const float*)d_in[20]; const float* ca_bv = (const float*)d_in[21];
  const float* ca_wo = (const float*)d_in[22]; const float* ca_bo = (const float*)d_in[23];
  const float* ca_nq = (const float*)d_in[24]; const float* ca_nk = (const float*)d_in[25];
  const float* n3_w  = (const float*)d_in[26]; const float* n3_b  = (const float*)d_in[27];
  const float* f_w1  = (const float*)d_in[28]; const float* f_b1  = (const float*)d_in[29];
  const float* f_w2  = (const float*)d_in[30]; const float* f_b2  = (const float*)d_in[31];

  char* ws = (char*)d_ws;
  float* em   = (float*)(ws + OFF_EM);
  float* bqkv = (float*)(ws + OFF_BQKV);
  float* bckv = (float*)(ws + OFF_BCKV);
  bf16* xn    = (bf16*)(ws + OFF_XN);
  bf16* qkvb  = (bf16*)(ws + OFF_QKV);
  bf16* caqb  = (bf16*)(ws + OFF_CAQ);
  bf16* kvb   = (bf16*)(ws + OFF_KV);
  bf16* qb    = (bf16*)(ws + OFF_QB);
  bf16* kb    = (bf16*)(ws + OFF_KB);
  bf16* yb    = (bf16*)(ws + OFF_YB);
  bf16* ctxb  = (bf16*)(ws + OFF_CTX);
  bf16* wbuf  = (bf16*)(ws + OFF_WBUF);
  bf16* hb    = (bf16*)(ws + OFF_HB);
  float* p0   = (float*)(ws + OFF_P0);
  float* xw   = (float*)d_out;

  const int M = BSZ * SLEN;   // 4096
  const int MC = BSZ * CTXL;  // 1024
  const float scl = 0.08838834764831845f;

#define TRANSO(W, Kd, Nd, noff) \
  transpose_w<<<dim3((Nd) / 64, (Kd) / 64), 256, 0, stream>>>(W, wbuf, Kd, Nd, noff)
#define GEMM256(Am, Md, Nd, Kd, ldA, ldB, kOff, bias, oF, oB, res, sc, prt, scs, rpb, mode) \
  gemm256<<<((Md) / 256) * ((Nd) / 256), 512, 0, stream>>>(Am, wbuf, bias, oF, oB, res, sc, prt, \
                                                           scs, rpb, (Nd) / 256, Nd, Kd, ldA, ldB, kOff, mode)
#define GEMM128(Am, Md, Nd, Kd, bias, oF, oB, res, sc, scs, rpb, mode) \
  gemm_bt<<<((Md) / 128) * ((Nd) / 128), 256, 0, stream>>>(Am, wbuf, bias, oF, oB, res, sc, scs, rpb, (Nd) / 128, Nd, Kd, mode)

  em_kernel<<<(BSZ * 6 * DIMX + 255) / 256, 256, 0, stream>>>(e, modu, em, BSZ * 6 * DIMX);
  cvt_kernel<<<(MC * DIMX / 8 + 255) / 256, 256, 0, stream>>>(context, ctxb, MC * DIMX / 8);
  packb_kernel<<<(3 * DIMX + 255) / 256, 256, 0, stream>>>(sa_bq, sa_bk, sa_bv, bqkv, 3 * DIMX);
  packb_kernel<<<(2 * DIMX + 255) / 256, 256, 0, stream>>>(ca_bk, ca_bv, nullptr, bckv, 2 * DIMX);

  // --- self attention ---
  ln_kernel<<<M, 256, 0, stream>>>(x, em + 1 * DIMX, em + 0 * DIMX, 6 * DIMX, 1.0f, SLEN, xn);

  TRANSO(sa_wq, DIMX, DIMX, 0);
  TRANSO(sa_wk, DIMX, DIMX, DIMX);
  TRANSO(sa_wv, DIMX, DIMX, 2 * DIMX);
  GEMM256(xn, M, 3 * DIMX, DIMX, DIMX, DIMX, 0, bqkv, nullptr, qkvb,
          nullptr, nullptr, nullptr, 0, 1, 1);
  rms_rope_kernel<<<M, 256, 0, stream>>>(qkvb, 3 * DIMX, sa_nq, fcos, fsin, 1, qb);
  rms_rope_kernel<<<M, 256, 0, stream>>>((bf16*)((short*)qkvb + DIMX), 3 * DIMX, sa_nk, fcos, fsin, 1, kb);

  attn_kernel<<<dim3(SLEN / 64, BSZ * NHEADS), 256, 0, stream>>>(
      qb, kb, (bf16*)((short*)qkvb + 2 * DIMX), yb, SLEN, SLEN, DIMX, DIMX, 3 * DIMX, scl);

  TRANSO(sa_wo, DIMX, DIMX, 0);
  GEMM256(yb, M, DIMX, DIMX, DIMX, DIMX, 0, sa_bo, xw, nullptr,
          x, em + 2 * DIMX, nullptr, 6 * DIMX, SLEN, 3);

  // --- cross attention ---
  ln_kernel<<<M, 256, 0, stream>>>(xw, n3_w, n3_b, 0, 0.0f, SLEN, xn);

  TRANSO(ca_wq, DIMX, DIMX, 0);
  GEMM256(xn, M, DIMX, DIMX, DIMX, DIMX, 0, ca_bq, nullptr, caqb,
          nullptr, nullptr, nullptr, 0, 1, 1);
  rms_rope_kernel<<<M, 256, 0, stream>>>(caqb, DIMX, ca_nq, fcos, fsin, 0, qb);

  TRANSO(ca_wk, DIMX, DIMX, 0);
  TRANSO(ca_wv, DIMX, DIMX, DIMX);
  GEMM128(ctxb, MC, 2 * DIMX, DIMX, bckv, nullptr, kvb, nullptr, nullptr, 0, 1, 1);
  rms_rope_kernel<<<MC, 256, 0, stream>>>(kvb, 2 * DIMX, ca_nk, fcos, fsin, 0, kb);

  attn_kernel<<<dim3(SLEN / 64, BSZ * NHEADS), 256, 0, stream>>>(
      qb, kb, (bf16*)((short*)kvb + DIMX), yb, SLEN, CTXL, DIMX, DIMX, 2 * DIMX, scl);

  TRANSO(ca_wo, DIMX, DIMX, 0);
  GEMM256(yb, M, DIMX, DIMX, DIMX, DIMX, 0, ca_bo, xw, nullptr,
          xw, nullptr, nullptr, 0, SLEN, 3);

  // --- FFN ---
  ln_kernel<<<M, 256, 0, stream>>>(xw, em + 4 * DIMX, em + 3 * DIMX, 6 * DIMX, 1.0f, SLEN, xn);

  TRANSO(f_w1, DIMX, FFND, 0);
  GEMM256(xn, M, FFND, DIMX, DIMX, DIMX, 0, f_b1, nullptr, hb,
          nullptr, nullptr, nullptr, 0, 1, 2);

  TRANSO(f_w2, FFND, DIMX, 0);
  // split-K: first half -> raw partial p0; second half fuses combine epilogue
  GEMM256(hb, M, DIMX, FFND / 2, FFND, FFND, 0, f_b2, p0, nullptr,
          nullptr, nullptr, nullptr, 0, 1, 0);
  GEMM256(hb, M, DIMX, FFND / 2, FFND, FFND, FFND / 2, f_b2, xw, nullptr,
          xw, em + 5 * DIMX, p0, 6 * DIMX, SLEN, 4);
}

// Round 6
// 1112.038 us; speedup vs baseline: 1.2356x; 1.2356x over previous
//
#include <hip/hip_runtime.h>
#include <hip/hip_bf16.h>
#include <math.h>

#define DIMX 2048
#define SLEN 2048
#define BSZ 2
#define NHEADS 16
#define HDIM 128
#define FFND 8192
#define CTXL 512
#define LN_EPS 1e-6f

typedef __attribute__((ext_vector_type(8))) short short8_t;
typedef __attribute__((ext_vector_type(4))) short short4_t;
typedef __attribute__((ext_vector_type(4))) float f32x4;
typedef __hip_bfloat16 bf16;

__device__ __forceinline__ short f2bf(float f) {
  union { float f; unsigned u; } v; v.f = f;
  return (short)((v.u + 0x7FFFu + ((v.u >> 16) & 1u)) >> 16);
}
__device__ __forceinline__ float bf2f(short s) {
  union { unsigned u; float f; } v; v.u = ((unsigned)(unsigned short)s) << 16;
  return v.f;
}

__device__ __forceinline__ void gload16(const void* g, void* l) {
  __builtin_amdgcn_global_load_lds(
      (const __attribute__((address_space(1))) unsigned int*)g,
      (__attribute__((address_space(3))) unsigned int*)l, 16, 0, 0);
}

__device__ __forceinline__ float wred_sum(float v) {
#pragma unroll
  for (int o = 32; o > 0; o >>= 1) v += __shfl_xor(v, o, 64);
  return v;
}

__global__ void em_kernel(const float* __restrict__ e, const float* __restrict__ mod,
                          float* __restrict__ em, int n) {
  int i = blockIdx.x * 256 + threadIdx.x;
  if (i < n) em[i] = e[i] + mod[i % (6 * DIMX)];
}

__global__ void cvt_kernel(const float* __restrict__ in, bf16* __restrict__ out, int n8) {
  int i = blockIdx.x * 256 + threadIdx.x;
  if (i >= n8) return;
  float4 a = *(const float4*)(in + (size_t)i * 8);
  float4 b = *(const float4*)(in + (size_t)i * 8 + 4);
  float fv[8] = {a.x, a.y, a.z, a.w, b.x, b.y, b.z, b.w};
  short8_t o;
#pragma unroll
  for (int j = 0; j < 8; ++j) o[j] = f2bf(fv[j]);
  *(short8_t*)((short*)out + (size_t)i * 8) = o;
}

__global__ void packb_kernel(const float* b0, const float* b1, const float* b2,
                             float* __restrict__ dst, int n) {
  int i = blockIdx.x * 256 + threadIdx.x;
  if (i >= n) return;
  int seg = i >> 11, j = i & 2047;
  const float* s = seg == 0 ? b0 : (seg == 1 ? b1 : b2);
  dst[i] = s[j];
}

// W fp32 [K][N] -> Wt bf16 [noff+N][K]
__global__ __launch_bounds__(256) void transpose_w(const float* __restrict__ W,
                                                   bf16* __restrict__ Wt, int K, int N,
                                                   int noff) {
  __shared__ short tile[64 * 68];
  int k0 = blockIdx.y << 6, n0 = blockIdx.x << 6;
  int t = threadIdx.x;
#pragma unroll
  for (int p = 0; p < 4; ++p) {
    int lin = p * 1024 + t * 4;
    int kr = lin >> 6, nc = lin & 63;
    float4 f = *(const float4*)(W + (size_t)(k0 + kr) * N + n0 + nc);
    tile[(nc + 0) * 68 + kr] = f2bf(f.x);
    tile[(nc + 1) * 68 + kr] = f2bf(f.y);
    tile[(nc + 2) * 68 + kr] = f2bf(f.z);
    tile[(nc + 3) * 68 + kr] = f2bf(f.w);
  }
  __syncthreads();
#pragma unroll
  for (int p = 0; p < 4; ++p) {
    int lin = p * 1024 + t * 4;
    int nr = lin >> 6, kc = lin & 63;
    short4_t s = *(const short4_t*)&tile[nr * 68 + kc];
    *(short4_t*)((short*)Wt + (size_t)(noff + n0 + nr) * K + k0 + kc) = s;
  }
}

__global__ __launch_bounds__(256) void ln_kernel(
    const float* __restrict__ x, const float* __restrict__ gamma,
    const float* __restrict__ beta, int gbstride, float addone,
    int rows_per_b, bf16* __restrict__ out) {
  int row = blockIdx.x;
  int t = threadIdx.x;
  const float* xr = x + (size_t)row * DIMX;
  float4 v0 = *(const float4*)(xr + t * 8);
  float4 v1 = *(const float4*)(xr + t * 8 + 4);
  float vv[8] = {v0.x, v0.y, v0.z, v0.w, v1.x, v1.y, v1.z, v1.w};
  float s = 0.f, ss = 0.f;
#pragma unroll
  for (int i = 0; i < 8; ++i) { s += vv[i]; ss += vv[i] * vv[i]; }
  __shared__ float red[8];
  s = wred_sum(s); ss = wred_sum(ss);
  int wid = t >> 6;
  if ((t & 63) == 0) { red[wid] = s; red[4 + wid] = ss; }
  __syncthreads();
  float sum = red[0] + red[1] + red[2] + red[3];
  float sumsq = red[4] + red[5] + red[6] + red[7];
  float mean = sum * (1.f / DIMX);
  float var = sumsq * (1.f / DIMX) - mean * mean;
  float rs = rsqrtf(var + LN_EPS);
  int b = row / rows_per_b;
  const float* g = gamma + (size_t)b * gbstride;
  const float* be = beta + (size_t)b * gbstride;
  short8_t o;
#pragma unroll
  for (int i = 0; i < 8; ++i) {
    int d = t * 8 + i;
    float y = (vv[i] - mean) * rs;
    o[i] = f2bf(y * (addone + g[d]) + be[d]);
  }
  *(short8_t*)((short*)out + (size_t)row * DIMX + t * 8) = o;
}

__global__ __launch_bounds__(256) void rms_rope_kernel(
    const bf16* __restrict__ x, int xstride, const float* __restrict__ w,
    const float* __restrict__ fcos, const float* __restrict__ fsin,
    int do_rope, bf16* __restrict__ out) {
  int row = blockIdx.x;
  int t = threadIdx.x;
  short8_t xi = *(const short8_t*)((const short*)x + (size_t)row * xstride + t * 8);
  float vv[8];
#pragma unroll
  for (int i = 0; i < 8; ++i) vv[i] = bf2f(xi[i]);
  float ss = 0.f;
#pragma unroll
  for (int i = 0; i < 8; ++i) ss += vv[i] * vv[i];
  __shared__ float red[4];
  ss = wred_sum(ss);
  int wid = t >> 6;
  if ((t & 63) == 0) red[wid] = ss;
  __syncthreads();
  float sumsq = red[0] + red[1] + red[2] + red[3];
  float rs = rsqrtf(sumsq * (1.f / DIMX) + LN_EPS);
  float y[8];
#pragma unroll
  for (int i = 0; i < 8; ++i) y[i] = vv[i] * rs * w[t * 8 + i];
  if (do_rope) {
    int s = row % SLEN;
    int f = s >> 8, hh = (s >> 4) & 15, ww = s & 15;
    int jb = ((t * 8) % HDIM) >> 1;
#pragma unroll
    for (int p = 0; p < 4; ++p) {
      int j = jb + p;
      int src = (j < 22) ? f : ((j < 43) ? hh : ww);
      float c = fcos[src * 64 + j];
      float sn = fsin[src * 64 + j];
      float xr_ = y[2 * p], xim = y[2 * p + 1];
      y[2 * p] = xr_ * c - xim * sn;
      y[2 * p + 1] = xr_ * sn + xim * c;
    }
  }
  short8_t o;
#pragma unroll
  for (int i = 0; i < 8; ++i) o[i] = f2bf(y[i]);
  *(short8_t*)((short*)out + (size_t)row * DIMX + t * 8) = o;
}

// ------------- 256x256 8-phase GEMM v3 (R4 skeleton + hoisted reads) -----
// Invariant (proven, R4-passed): at each tile boundary (vmcnt(4)+BAR),
// ALL of tile t+1 has landed; outstanding = {Ae(t+2), Be(t+2)}.
// Per tile: reads a_e,b_e at tile start; b_l hoisted into ph0; a_l into ph1;
// ph3 reuses b_e from registers.  24 ds_read_b128/tile.  Every hoisted read
// targets a landed region and drains >=1 barrier before that region restages.
#define RDA(dst, bufI, mh) { _Pragma("unroll") for (int mi = 0; mi < 4; ++mi) { \
    int r = wm * 128 + (mh) * 64 + mi * 16 + l15; int rb = r * 64; int r7 = r & 7; \
    dst[mi][0] = *(const short8_t*)&As[bufI][rb + ((koff ^ r7) << 3)]; \
    dst[mi][1] = *(const short8_t*)&As[bufI][rb + (((4 + koff) ^ r7) << 3)]; } }
#define RDB(dst, bufI, nh) { _Pragma("unroll") for (int nj = 0; nj < 2; ++nj) { \
    int r = wn * 64 + (nh) * 32 + nj * 16 + l15; int rb = r * 64; int r7 = r & 7; \
    dst[nj][0] = *(const short8_t*)&Bs[bufI][rb + ((koff ^ r7) << 3)]; \
    dst[nj][1] = *(const short8_t*)&Bs[bufI][rb + (((4 + koff) ^ r7) << 3)]; } }
#define MMAQ(aS, bS, mh, nh) { _Pragma("unroll") for (int kq = 0; kq < 2; ++kq) \
    _Pragma("unroll") for (int mi = 0; mi < 4; ++mi) \
    _Pragma("unroll") for (int nj = 0; nj < 2; ++nj) \
      acc[(mh)*4+mi][(nh)*2+nj] = __builtin_amdgcn_mfma_f32_16x16x32_bf16( \
          aS[mi][kq], bS[nj][kq], acc[(mh)*4+mi][(nh)*2+nj], 0, 0, 0); }
#define BAR asm volatile("s_barrier" ::: "memory")
#define VMCNT(n) asm volatile("s_waitcnt vmcnt(" #n ")" ::: "memory")
#define SETPRIO(x) __builtin_amdgcn_s_setprio(x)

__global__ __launch_bounds__(512) void gemm256(
    const bf16* __restrict__ A, const bf16* __restrict__ Bt,
    const float* __restrict__ bias,
    float* outF, bf16* outB,
    const float* resid, const float* __restrict__ scale,
    int scstride, int rows_per_b, int gn, int N, int K, int mode) {
  __shared__ short As[2][16384];
  __shared__ short Bs[2][16384];
  int t = threadIdx.x, lane = t & 63, wv = t >> 6;
  int l15 = lane & 15, koff = lane >> 4;
  int wm = wv >> 2, wn = wv & 3;
  int nwg = gridDim.x, cpx = nwg >> 3;
  int swz = (blockIdx.x & 7) * cpx + (blockIdx.x >> 3);
  int by = swz / gn, bx = swz % gn;
  int m0 = by << 8, n0 = bx << 8;

  f32x4 acc[8][4] = {};
  short8_t ae[4][2], al[4][2], be[2][2], bl[2][2];

  int srcChunk = ((lane & 7) ^ (lane >> 3)) << 3;
  int rowInSlot = lane >> 3;
  const short* Ap = (const short*)A;
  const short* Bp = (const short*)Bt;

  auto stageA = [&](int bufI, int kkE, int late) {
#pragma unroll
    for (int i = 0; i < 2; ++i) {
      int idx = i * 8 + wv;
      int slot = ((idx >> 3) << 4) + (idx & 7) + (late ? 8 : 0);
      int row = slot * 8 + rowInSlot;
      gload16(Ap + (size_t)(m0 + row) * K + kkE + srcChunk, &As[bufI][slot << 9]);
    }
  };
  auto stageB = [&](int bufI, int kkE, int late) {
#pragma unroll
    for (int i = 0; i < 2; ++i) {
      int idx = i * 8 + wv;
      int slot = ((idx >> 2) << 3) + (idx & 3) + (late ? 4 : 0);
      int row = slot * 8 + rowInSlot;
      gload16(Bp + (size_t)(n0 + row) * K + kkE + srcChunk, &Bs[bufI][slot << 9]);
    }
  };

  int NT = K >> 6;
  // prologue: tile0 all 4 halves + tile1 early halves (12 loads/thread)
  stageA(0, 0, 0); stageB(0, 0, 0); stageA(0, 0, 1); stageB(0, 0, 1);
  stageA(1, 64, 0); stageB(1, 64, 0);
  VMCNT(4);  // tile0 fully landed; outstanding = Ae(1),Be(1)
  BAR;

  for (int tt = 0; tt < NT; ++tt) {
    int buf = tt & 1;
    int k1 = ((tt + 1) < NT ? (tt + 1) : 0) << 6;
    int k2 = ((tt + 2) < NT ? (tt + 2) : 0) << 6;
    // tile start: read ph0 operands (regions landed by boundary invariant)
    RDA(ae, buf, 0); RDB(be, buf, 0);
    // ph0: stage Al(t+1); MFMA (mh0,nh0); hoist read b_late
    stageA(buf ^ 1, k1, 1);
    BAR; SETPRIO(1); MMAQ(ae, be, 0, 0); SETPRIO(0);
    RDB(bl, buf, 1);
    BAR;
    // ph1: stage Bl(t+1); MFMA (mh0,nh1); hoist read a_late
    stageB(buf ^ 1, k1, 1);
    BAR; SETPRIO(1); MMAQ(ae, bl, 0, 1); SETPRIO(0);
    RDA(al, buf, 1);
    BAR;
    // ph2: stage Ae(t+2); MFMA (mh1,nh1)
    stageA(buf, k2, 0);
    BAR; SETPRIO(1); MMAQ(al, bl, 1, 1); SETPRIO(0); BAR;
    // ph3: stage Be(t+2); MFMA (mh1,nh0) reusing b_early from regs
    stageB(buf, k2, 0);
    BAR; SETPRIO(1); MMAQ(al, be, 1, 0); SETPRIO(0);
    VMCNT(4);  // tile t+1 fully landed
    BAR;
  }
  VMCNT(0);  // drain tail garbage stages

  int mo = m0 + wm * 128, no = n0 + wn * 64;
#pragma unroll
  for (int mf = 0; mf < 8; ++mf)
#pragma unroll
    for (int nf = 0; nf < 4; ++nf) {
      int n = no + nf * 16 + l15;
      float bia = bias[n];
#pragma unroll
      for (int r = 0; r < 4; ++r) {
        int m = mo + mf * 16 + koff * 4 + r;
        float vv = acc[mf][nf][r] + bia;
        size_t idx = (size_t)m * N + n;
        if (mode == 1) {
          ((short*)outB)[idx] = f2bf(vv);
        } else if (mode == 2) {
          float g = 0.5f * vv * (1.f + tanhf(0.7978845608f * (vv + 0.044715f * vv * vv * vv)));
          ((short*)outB)[idx] = f2bf(g);
        } else {
          float sc = scale ? scale[(size_t)(m / rows_per_b) * scstride + n] : 1.0f;
          outF[idx] = resid[idx] + vv * sc;
        }
      }
    }
}

// ---------------- 128x128 2-phase GEMM (proven R3) --------
__global__ __launch_bounds__(256) void gemm_bt(
    const bf16* __restrict__ A, const bf16* __restrict__ Bt,
    const float* __restrict__ bias,
    float* outF, bf16* outB,
    const float* resid, const float* __restrict__ scale,
    int scstride, int rows_per_b, int gn, int N, int K, int mode) {
  __shared__ short As[2][128 * 64];
  __shared__ short Bs[2][128 * 64];
  int t = threadIdx.x, lane = t & 63, wv = t >> 6;
  int nwg = gridDim.x, cpx = nwg >> 3;
  int swz = (blockIdx.x & 7) * cpx + (blockIdx.x >> 3);
  int by = swz / gn, bx = swz % gn;
  int m0 = by << 7, n0 = bx << 7;
  f32x4 acc[4][4] = {};
  int mo_l = (wv >> 1) << 6, no_l = (wv & 1) << 6;

  int srow[4], scol[4];
#pragma unroll
  for (int j = 0; j < 4; ++j) {
    srow[j] = wv * 32 + j * 8 + (lane >> 3);
    scol[j] = ((lane & 7) ^ (srow[j] & 7)) << 3;
  }
  const short* Ap = (const short*)A;
  const short* Bp = (const short*)Bt;

  int koff = lane >> 4;
  int rowA[4], rowB[4];
#pragma unroll
  for (int i = 0; i < 4; ++i) {
    rowA[i] = mo_l + i * 16 + (lane & 15);
    rowB[i] = no_l + i * 16 + (lane & 15);
  }

  auto stage = [&](int bufI, int kk) {
#pragma unroll
    for (int j = 0; j < 4; ++j) {
      gload16(Ap + (size_t)(m0 + srow[j]) * K + kk + scol[j],
              &As[bufI][(wv * 32 + j * 8) * 64]);
      gload16(Bp + (size_t)(n0 + srow[j]) * K + kk + scol[j],
              &Bs[bufI][(wv * 32 + j * 8) * 64]);
    }
  };

  stage(0, 0);
  __syncthreads();
  int cur = 0;
  for (int kk = 0; kk < K; kk += 64) {
    int nxt = cur ^ 1;
    if (kk + 64 < K) stage(nxt, kk + 64);
    short8_t af[2][4], bfv[2][4];
#pragma unroll
    for (int h = 0; h < 2; ++h)
#pragma unroll
      for (int i = 0; i < 4; ++i) {
        int cA = ((h * 4 + koff) ^ (rowA[i] & 7)) << 3;
        af[h][i] = *(const short8_t*)&As[cur][rowA[i] * 64 + cA];
        int cB = ((h * 4 + koff) ^ (rowB[i] & 7)) << 3;
        bfv[h][i] = *(const short8_t*)&Bs[cur][rowB[i] * 64 + cB];
      }
#pragma unroll
    for (int h = 0; h < 2; ++h)
#pragma unroll
      for (int mt = 0; mt < 4; ++mt)
#pragma unroll
        for (int nt = 0; nt < 4; ++nt)
          acc[mt][nt] = __builtin_amdgcn_mfma_f32_16x16x32_bf16(af[h][mt], bfv[h][nt], acc[mt][nt], 0, 0, 0);
    __syncthreads();
    cur = nxt;
  }

  int mo = m0 + mo_l, no = n0 + no_l;
#pragma unroll
  for (int mt = 0; mt < 4; ++mt)
#pragma unroll
    for (int nt = 0; nt < 4; ++nt) {
      int n = no + nt * 16 + (lane & 15);
      float bia = bias[n];
#pragma unroll
      for (int r = 0; r < 4; ++r) {
        int m = mo + mt * 16 + (lane >> 4) * 4 + r;
        float vv = acc[mt][nt][r] + bia;
        size_t idx = (size_t)m * N + n;
        if (mode == 1) {
          ((short*)outB)[idx] = f2bf(vv);
        } else if (mode == 2) {
          float g = 0.5f * vv * (1.f + tanhf(0.7978845608f * (vv + 0.044715f * vv * vv * vv)));
          ((short*)outB)[idx] = f2bf(g);
        } else {
          float sc = scale ? scale[(size_t)(m / rows_per_b) * scstride + n] : 1.0f;
          outF[idx] = resid[idx] + vv * sc;
        }
      }
    }
}

// Flash attention with strided q/k/v inputs
__global__ __launch_bounds__(256) void attn_kernel(
    const bf16* __restrict__ q, const bf16* __restrict__ k,
    const bf16* __restrict__ v, bf16* __restrict__ y,
    int QL, int KVL, int qs, int ks, int vs, float scl) {
  __shared__ short Kt[64 * 136];
  __shared__ short Vt[128 * 72];
  __shared__ short Pl[4 * 16 * 72];
  __shared__ float rl[4 * 16];
  __shared__ float ll[4 * 16];
  int t = threadIdx.x, lane = t & 63, wv = t >> 6;
  int bh = blockIdx.y;
  int b = bh / NHEADS, h = bh % NHEADS;
  int q0 = blockIdx.x * 64 + wv * 16;
  const short* qp = (const short*)q;
  const short* kp = (const short*)k;
  const short* vp = (const short*)v;
  short8_t qf[4];
  {
    size_t qbase = ((size_t)(b * QL) + q0 + (lane & 15)) * qs + h * HDIM + (lane >> 4) * 8;
#pragma unroll
    for (int kc = 0; kc < 4; ++kc) qf[kc] = *(const short8_t*)(qp + qbase + kc * 32);
  }
  f32x4 o[8] = {};
  float m_run = -1e30f, l_run = 0.f;
  int strow = t >> 2, stcol = (t & 3) * 32;
  for (int kt0 = 0; kt0 < KVL; kt0 += 64) {
    const short* ksrc = kp + ((size_t)(b * KVL + kt0 + strow) * ks + h * HDIM + stcol);
    const short* vsrc = vp + ((size_t)(b * KVL + kt0 + strow) * vs + h * HDIM + stcol);
#pragma unroll
    for (int c = 0; c < 4; ++c)
      *(short8_t*)&Kt[strow * 136 + stcol + c * 8] = *(const short8_t*)(ksrc + c * 8);
#pragma unroll
    for (int c = 0; c < 4; ++c) {
      short8_t vvv = *(const short8_t*)(vsrc + c * 8);
#pragma unroll
      for (int e = 0; e < 8; ++e) Vt[(stcol + c * 8 + e) * 72 + strow] = vvv[e];
    }
    __syncthreads();
    f32x4 st[4];
#pragma unroll
    for (int kt = 0; kt < 4; ++kt) {
      f32x4 aa = {0.f, 0.f, 0.f, 0.f};
#pragma unroll
      for (int kc = 0; kc < 4; ++kc) {
        short8_t kf = *(const short8_t*)&Kt[(kt * 16 + (lane & 15)) * 136 + kc * 32 + (lane >> 4) * 8];
        aa = __builtin_amdgcn_mfma_f32_16x16x32_bf16(kf, qf[kc], aa, 0, 0, 0);
      }
      st[kt] = aa;
    }
    float mt_ = -1e30f;
#pragma unroll
    for (int kt = 0; kt < 4; ++kt)
#pragma unroll
      for (int r = 0; r < 4; ++r) mt_ = fmaxf(mt_, st[kt][r]);
    mt_ = fmaxf(mt_, __shfl_xor(mt_, 16, 64));
    mt_ = fmaxf(mt_, __shfl_xor(mt_, 32, 64));
    mt_ *= scl;
    float m_new = fmaxf(m_run, mt_);
    float rfac = __expf(m_run - m_new);
    float ps = 0.f;
#pragma unroll
    for (int kt = 0; kt < 4; ++kt)
#pragma unroll
      for (int r = 0; r < 4; ++r) {
        float p = __expf(st[kt][r] * scl - m_new);
        st[kt][r] = p;
        ps += p;
      }
    ps += __shfl_xor(ps, 16, 64);
    ps += __shfl_xor(ps, 32, 64);
    l_run = l_run * rfac + ps;
    m_run = m_new;
    if (lane < 16) rl[wv * 16 + lane] = rfac;
#pragma unroll
    for (int kt = 0; kt < 4; ++kt)
#pragma unroll
      for (int r = 0; r < 4; ++r)
        Pl[(wv * 16 + (lane & 15)) * 72 + kt * 16 + (lane >> 4) * 4 + r] = f2bf(st[kt][r]);
    float rr[4];
#pragma unroll
    for (int r = 0; r < 4; ++r) rr[r] = rl[wv * 16 + (lane >> 4) * 4 + r];
#pragma unroll
    for (int dt = 0; dt < 8; ++dt)
#pragma unroll
      for (int r = 0; r < 4; ++r) o[dt][r] *= rr[r];
#pragma unroll
    for (int kc2 = 0; kc2 < 2; ++kc2) {
      short8_t pa = *(const short8_t*)&Pl[(wv * 16 + (lane & 15)) * 72 + kc2 * 32 + (lane >> 4) * 8];
#pragma unroll
      for (int dt = 0; dt < 8; ++dt) {
        short8_t vf = *(const short8_t*)&Vt[(dt * 16 + (lane & 15)) * 72 + kc2 * 32 + (lane >> 4) * 8];
        o[dt] = __builtin_amdgcn_mfma_f32_16x16x32_bf16(pa, vf, o[dt], 0, 0, 0);
      }
    }
    __syncthreads();
  }
  if (lane < 16) ll[wv * 16 + lane] = 1.f / l_run;
  float li[4];
#pragma unroll
  for (int r = 0; r < 4; ++r) li[r] = ll[wv * 16 + (lane >> 4) * 4 + r];
  short* yp = (short*)y;
#pragma unroll
  for (int dt = 0; dt < 8; ++dt)
#pragma unroll
    for (int r = 0; r < 4; ++r) {
      int qq = q0 + (lane >> 4) * 4 + r;
      int d = dt * 16 + (lane & 15);
      yp[((size_t)(b * QL) + qq) * DIMX + h * HDIM + d] = f2bf(o[dt][r] * li[r]);
    }
}

// ws layout (bytes)
#define OFF_EM    0ull
#define OFF_BQKV  (512ull << 10)
#define OFF_BCKV  (560ull << 10)
#define OFF_XN    (1ull << 20)
#define OFF_QKV   (17ull << 20)
#define OFF_CAQ   (17ull << 20)
#define OFF_KV    (33ull << 20)
#define OFF_QB    (65ull << 20)
#define OFF_KB    (81ull << 20)
#define OFF_YB    (97ull << 20)
#define OFF_CTX   (113ull << 20)
#define OFF_WBUF  (117ull << 20)
#define OFF_HB    (17ull << 20)

extern "C" void kernel_launch(void* const* d_in, const int* in_sizes, int n_in,
                              void* d_out, int out_size, void* d_ws, size_t ws_size,
                              hipStream_t stream) {
  const float* x       = (const float*)d_in[0];
  const float* e       = (const float*)d_in[1];
  const float* context = (const float*)d_in[2];
  const float* fcos    = (const float*)d_in[3];
  const float* fsin    = (const float*)d_in[4];
  const float* modu    = (const float*)d_in[5];
  const float* sa_wq = (const float*)d_in[6];  const float* sa_bq = (const float*)d_in[7];
  const float* sa_wk = (const float*)d_in[8];  const float* sa_bk = (const float*)d_in[9];
  const float* sa_wv = (const float*)d_in[10]; const float* sa_bv = (const float*)d_in[11];
  const float* sa_wo = (const float*)d_in[12]; const float* sa_bo = (const float*)d_in[13];
  const float* sa_nq = (const float*)d_in[14]; const float* sa_nk = (const float*)d_in[15];
  const float* ca_wq = (const float*)d_in[16]; const float* ca_bq = (const float*)d_in[17];
  const float* ca_wk = (const float*)d_in[18]; const float* ca_bk = (const float*)d_in[19];
  const float* ca_wv = (const float*)d_in[20]; const float* ca_bv = (const float*)d_in[21];
  const float* ca_wo = (const float*)d_in[22]; const float* ca_bo = (const float*)d_in[23];
  const float* ca_nq = (const float*)d_in[24]; const float* ca_nk = (const float*)d_in[25];
  const float* n3_w  = (const float*)d_in[26]; const float* n3_b  = (const float*)d_in[27];
  const float* f_w1  = (const float*)d_in[28]; const float* f_b1  = (const float*)d_in[29];
  const float* f_w2  = (const float*)d_in[30]; const float* f_b2  = (const float*)d_in[31];

  char* ws = (char*)d_ws;
  float* em   = (float*)(ws + OFF_EM);
  float* bqkv = (float*)(ws + OFF_BQKV);
  float* bckv = (float*)(ws + OFF_BCKV);
  bf16* xn    = (bf16*)(ws + OFF_XN);
  bf16* qkvb  = (bf16*)(ws + OFF_QKV);
  bf16* caqb  = (bf16*)(ws + OFF_CAQ);
  bf16* kvb   = (bf16*)(ws + OFF_KV);
  bf16* qb    = (bf16*)(ws + OFF_QB);
  bf16* kb    = (bf16*)(ws + OFF_KB);
  bf16* yb    = (bf16*)(ws + OFF_YB);
  bf16* ctxb  = (bf16*)(ws + OFF_CTX);
  bf16* wbuf  = (bf16*)(ws + OFF_WBUF);
  bf16* hb    = (bf16*)(ws + OFF_HB);
  float* xw   = (float*)d_out;

  const int M = BSZ * SLEN;
  const int MC = BSZ * CTXL;
  const float scl = 0.08838834764831845f;

#define TRANSO(W, Kd, Nd, noff) \
  transpose_w<<<dim3((Nd) / 64, (Kd) / 64), 256, 0, stream>>>(W, wbuf, Kd, Nd, noff)
#define GEMM256(Am, Md, Nd, Kd, bias, oF, oB, res, sc, scs, rpb, mode) \
  gemm256<<<((Md) / 256) * ((Nd) / 256), 512, 0, stream>>>(Am, wbuf, bias, oF, oB, res, sc, \
                                                           scs, rpb, (Nd) / 256, Nd, Kd, mode)
#define GEMM128(Am, Md, Nd, Kd, bias, oF, oB, res, sc, scs, rpb, mode) \
  gemm_bt<<<((Md) / 128) * ((Nd) / 128), 256, 0, stream>>>(Am, wbuf, bias, oF, oB, res, sc, scs, rpb, (Nd) / 128, Nd, Kd, mode)

  em_kernel<<<(BSZ * 6 * DIMX + 255) / 256, 256, 0, stream>>>(e, modu, em, BSZ * 6 * DIMX);
  cvt_kernel<<<(MC * DIMX / 8 + 255) / 256, 256, 0, stream>>>(context, ctxb, MC * DIMX / 8);
  packb_kernel<<<(3 * DIMX + 255) / 256, 256, 0, stream>>>(sa_bq, sa_bk, sa_bv, bqkv, 3 * DIMX);
  packb_kernel<<<(2 * DIMX + 255) / 256, 256, 0, stream>>>(ca_bk, ca_bv, nullptr, bckv, 2 * DIMX);

  // --- self attention ---
  ln_kernel<<<M, 256, 0, stream>>>(x, em + 1 * DIMX, em + 0 * DIMX, 6 * DIMX, 1.0f, SLEN, xn);

  TRANSO(sa_wq, DIMX, DIMX, 0);
  TRANSO(sa_wk, DIMX, DIMX, DIMX);
  TRANSO(sa_wv, DIMX, DIMX, 2 * DIMX);
  GEMM256(xn, M, 3 * DIMX, DIMX, bqkv, nullptr, qkvb, nullptr, nullptr, 0, 1, 1);
  rms_rope_kernel<<<M, 256, 0, stream>>>(qkvb, 3 * DIMX, sa_nq, fcos, fsin, 1, qb);
  rms_rope_kernel<<<M, 256, 0, stream>>>((bf16*)((short*)qkvb + DIMX), 3 * DIMX, sa_nk, fcos, fsin, 1, kb);

  attn_kernel<<<dim3(SLEN / 64, BSZ * NHEADS), 256, 0, stream>>>(
      qb, kb, (bf16*)((short*)qkvb + 2 * DIMX), yb, SLEN, SLEN, DIMX, DIMX, 3 * DIMX, scl);

  TRANSO(sa_wo, DIMX, DIMX, 0);
  GEMM128(yb, M, DIMX, DIMX, sa_bo, xw, nullptr, x, em + 2 * DIMX, 6 * DIMX, SLEN, 3);

  // --- cross attention ---
  ln_kernel<<<M, 256, 0, stream>>>(xw, n3_w, n3_b, 0, 0.0f, SLEN, xn);

  TRANSO(ca_wq, DIMX, DIMX, 0);
  GEMM128(xn, M, DIMX, DIMX, ca_bq, nullptr, caqb, nullptr, nullptr, 0, 1, 1);
  rms_rope_kernel<<<M, 256, 0, stream>>>(caqb, DIMX, ca_nq, fcos, fsin, 0, qb);

  TRANSO(ca_wk, DIMX, DIMX, 0);
  TRANSO(ca_wv, DIMX, DIMX, DIMX);
  GEMM128(ctxb, MC, 2 * DIMX, DIMX, bckv, nullptr, kvb, nullptr, nullptr, 0, 1, 1);
  rms_rope_kernel<<<MC, 256, 0, stream>>>(kvb, 2 * DIMX, ca_nk, fcos, fsin, 0, kb);

  attn_kernel<<<dim3(SLEN / 64, BSZ * NHEADS), 256, 0, stream>>>(
      qb, kb, (bf16*)((short*)kvb + DIMX), yb, SLEN, CTXL, DIMX, DIMX, 2 * DIMX, scl);

  TRANSO(ca_wo, DIMX, DIMX, 0);
  GEMM128(yb, M, DIMX, DIMX, ca_bo, xw, nullptr, xw, nullptr, 0, SLEN, 3);

  // --- FFN ---
  ln_kernel<<<M, 256, 0, stream>>>(xw, em + 4 * DIMX, em + 3 * DIMX, 6 * DIMX, 1.0f, SLEN, xn);

  TRANSO(f_w1, DIMX, FFND, 0);
  GEMM256(xn, M, FFND, DIMX, f_b1, nullptr, hb, nullptr, nullptr, 0, 1, 2);

  TRANSO(f_w2, FFND, DIMX, 0);
  GEMM128(hb, M, DIMX, FFND, f_b2, xw, nullptr, xw, em + 5 * DIMX, 6 * DIMX, SLEN, 3);
}

// Round 7
// 1082.076 us; speedup vs baseline: 1.2698x; 1.0277x over previous
//
#include <hip/hip_runtime.h>
#include <hip/hip_bf16.h>
#include <math.h>

#define DIMX 2048
#define SLEN 2048
#define BSZ 2
#define NHEADS 16
#define HDIM 128
#define FFND 8192
#define CTXL 512
#define LN_EPS 1e-6f

typedef __attribute__((ext_vector_type(8))) short short8_t;
typedef __attribute__((ext_vector_type(4))) short short4_t;
typedef __attribute__((ext_vector_type(4))) float f32x4;
typedef __hip_bfloat16 bf16;

__device__ __forceinline__ short f2bf(float f) {
  union { float f; unsigned u; } v; v.f = f;
  return (short)((v.u + 0x7FFFu + ((v.u >> 16) & 1u)) >> 16);
}
__device__ __forceinline__ float bf2f(short s) {
  union { unsigned u; float f; } v; v.u = ((unsigned)(unsigned short)s) << 16;
  return v.f;
}

__device__ __forceinline__ void gload16(const void* g, void* l) {
  __builtin_amdgcn_global_load_lds(
      (const __attribute__((address_space(1))) unsigned int*)g,
      (__attribute__((address_space(3))) unsigned int*)l, 16, 0, 0);
}

__device__ __forceinline__ float wred_sum(float v) {
#pragma unroll
  for (int o = 32; o > 0; o >>= 1) v += __shfl_xor(v, o, 64);
  return v;
}

__global__ void em_kernel(const float* __restrict__ e, const float* __restrict__ mod,
                          float* __restrict__ em, int n) {
  int i = blockIdx.x * 256 + threadIdx.x;
  if (i < n) em[i] = e[i] + mod[i % (6 * DIMX)];
}

__global__ void cvt_kernel(const float* __restrict__ in, bf16* __restrict__ out, int n8) {
  int i = blockIdx.x * 256 + threadIdx.x;
  if (i >= n8) return;
  float4 a = *(const float4*)(in + (size_t)i * 8);
  float4 b = *(const float4*)(in + (size_t)i * 8 + 4);
  float fv[8] = {a.x, a.y, a.z, a.w, b.x, b.y, b.z, b.w};
  short8_t o;
#pragma unroll
  for (int j = 0; j < 8; ++j) o[j] = f2bf(fv[j]);
  *(short8_t*)((short*)out + (size_t)i * 8) = o;
}

__global__ void packb_kernel(const float* b0, const float* b1, const float* b2,
                             float* __restrict__ dst, int n) {
  int i = blockIdx.x * 256 + threadIdx.x;
  if (i >= n) return;
  int seg = i >> 11, j = i & 2047;
  const float* s = seg == 0 ? b0 : (seg == 1 ? b1 : b2);
  dst[i] = s[j];
}

// W fp32 [K][N] -> Wt bf16 [noff+N][K]
__global__ __launch_bounds__(256) void transpose_w(const float* __restrict__ W,
                                                   bf16* __restrict__ Wt, int K, int N,
                                                   int noff) {
  __shared__ short tile[64 * 68];
  int k0 = blockIdx.y << 6, n0 = blockIdx.x << 6;
  int t = threadIdx.x;
#pragma unroll
  for (int p = 0; p < 4; ++p) {
    int lin = p * 1024 + t * 4;
    int kr = lin >> 6, nc = lin & 63;
    float4 f = *(const float4*)(W + (size_t)(k0 + kr) * N + n0 + nc);
    tile[(nc + 0) * 68 + kr] = f2bf(f.x);
    tile[(nc + 1) * 68 + kr] = f2bf(f.y);
    tile[(nc + 2) * 68 + kr] = f2bf(f.z);
    tile[(nc + 3) * 68 + kr] = f2bf(f.w);
  }
  __syncthreads();
#pragma unroll
  for (int p = 0; p < 4; ++p) {
    int lin = p * 1024 + t * 4;
    int nr = lin >> 6, kc = lin & 63;
    short4_t s = *(const short4_t*)&tile[nr * 68 + kc];
    *(short4_t*)((short*)Wt + (size_t)(noff + n0 + nr) * K + k0 + kc) = s;
  }
}

__global__ __launch_bounds__(256) void ln_kernel(
    const float* __restrict__ x, const float* __restrict__ gamma,
    const float* __restrict__ beta, int gbstride, float addone,
    int rows_per_b, bf16* __restrict__ out) {
  int row = blockIdx.x;
  int t = threadIdx.x;
  const float* xr = x + (size_t)row * DIMX;
  float4 v0 = *(const float4*)(xr + t * 8);
  float4 v1 = *(const float4*)(xr + t * 8 + 4);
  float vv[8] = {v0.x, v0.y, v0.z, v0.w, v1.x, v1.y, v1.z, v1.w};
  float s = 0.f, ss = 0.f;
#pragma unroll
  for (int i = 0; i < 8; ++i) { s += vv[i]; ss += vv[i] * vv[i]; }
  __shared__ float red[8];
  s = wred_sum(s); ss = wred_sum(ss);
  int wid = t >> 6;
  if ((t & 63) == 0) { red[wid] = s; red[4 + wid] = ss; }
  __syncthreads();
  float sum = red[0] + red[1] + red[2] + red[3];
  float sumsq = red[4] + red[5] + red[6] + red[7];
  float mean = sum * (1.f / DIMX);
  float var = sumsq * (1.f / DIMX) - mean * mean;
  float rs = rsqrtf(var + LN_EPS);
  int b = row / rows_per_b;
  const float* g = gamma + (size_t)b * gbstride;
  const float* be = beta + (size_t)b * gbstride;
  short8_t o;
#pragma unroll
  for (int i = 0; i < 8; ++i) {
    int d = t * 8 + i;
    float y = (vv[i] - mean) * rs;
    o[i] = f2bf(y * (addone + g[d]) + be[d]);
  }
  *(short8_t*)((short*)out + (size_t)row * DIMX + t * 8) = o;
}

__global__ __launch_bounds__(256) void rms_rope_kernel(
    const bf16* __restrict__ x, int xstride, const float* __restrict__ w,
    const float* __restrict__ fcos, const float* __restrict__ fsin,
    int do_rope, bf16* __restrict__ out) {
  int row = blockIdx.x;
  int t = threadIdx.x;
  short8_t xi = *(const short8_t*)((const short*)x + (size_t)row * xstride + t * 8);
  float vv[8];
#pragma unroll
  for (int i = 0; i < 8; ++i) vv[i] = bf2f(xi[i]);
  float ss = 0.f;
#pragma unroll
  for (int i = 0; i < 8; ++i) ss += vv[i] * vv[i];
  __shared__ float red[4];
  ss = wred_sum(ss);
  int wid = t >> 6;
  if ((t & 63) == 0) red[wid] = ss;
  __syncthreads();
  float sumsq = red[0] + red[1] + red[2] + red[3];
  float rs = rsqrtf(sumsq * (1.f / DIMX) + LN_EPS);
  float y[8];
#pragma unroll
  for (int i = 0; i < 8; ++i) y[i] = vv[i] * rs * w[t * 8 + i];
  if (do_rope) {
    int s = row % SLEN;
    int f = s >> 8, hh = (s >> 4) & 15, ww = s & 15;
    int jb = ((t * 8) % HDIM) >> 1;
#pragma unroll
    for (int p = 0; p < 4; ++p) {
      int j = jb + p;
      int src = (j < 22) ? f : ((j < 43) ? hh : ww);
      float c = fcos[src * 64 + j];
      float sn = fsin[src * 64 + j];
      float xr_ = y[2 * p], xim = y[2 * p + 1];
      y[2 * p] = xr_ * c - xim * sn;
      y[2 * p + 1] = xr_ * sn + xim * c;
    }
  }
  short8_t o;
#pragma unroll
  for (int i = 0; i < 8; ++i) o[i] = f2bf(y[i]);
  *(short8_t*)((short*)out + (size_t)row * DIMX + t * 8) = o;
}

// ------------- 256x256 8-phase GEMM v3 (passed R6) -----
#define RDA(dst, bufI, mh) { _Pragma("unroll") for (int mi = 0; mi < 4; ++mi) { \
    int r = wm * 128 + (mh) * 64 + mi * 16 + l15; int rb = r * 64; int r7 = r & 7; \
    dst[mi][0] = *(const short8_t*)&As[bufI][rb + ((koff ^ r7) << 3)]; \
    dst[mi][1] = *(const short8_t*)&As[bufI][rb + (((4 + koff) ^ r7) << 3)]; } }
#define RDB(dst, bufI, nh) { _Pragma("unroll") for (int nj = 0; nj < 2; ++nj) { \
    int r = wn * 64 + (nh) * 32 + nj * 16 + l15; int rb = r * 64; int r7 = r & 7; \
    dst[nj][0] = *(const short8_t*)&Bs[bufI][rb + ((koff ^ r7) << 3)]; \
    dst[nj][1] = *(const short8_t*)&Bs[bufI][rb + (((4 + koff) ^ r7) << 3)]; } }
#define MMAQ(aS, bS, mh, nh) { _Pragma("unroll") for (int kq = 0; kq < 2; ++kq) \
    _Pragma("unroll") for (int mi = 0; mi < 4; ++mi) \
    _Pragma("unroll") for (int nj = 0; nj < 2; ++nj) \
      acc[(mh)*4+mi][(nh)*2+nj] = __builtin_amdgcn_mfma_f32_16x16x32_bf16( \
          aS[mi][kq], bS[nj][kq], acc[(mh)*4+mi][(nh)*2+nj], 0, 0, 0); }
#define BAR asm volatile("s_barrier" ::: "memory")
#define VMCNT(n) asm volatile("s_waitcnt vmcnt(" #n ")" ::: "memory")
#define SETPRIO(x) __builtin_amdgcn_s_setprio(x)

__global__ __launch_bounds__(512) void gemm256(
    const bf16* __restrict__ A, const bf16* __restrict__ Bt,
    const float* __restrict__ bias,
    float* outF, bf16* outB,
    const float* resid, const float* __restrict__ scale,
    int scstride, int rows_per_b, int gn, int N, int K, int mode) {
  __shared__ short As[2][16384];
  __shared__ short Bs[2][16384];
  int t = threadIdx.x, lane = t & 63, wv = t >> 6;
  int l15 = lane & 15, koff = lane >> 4;
  int wm = wv >> 2, wn = wv & 3;
  int nwg = gridDim.x, cpx = nwg >> 3;
  int swz = (blockIdx.x & 7) * cpx + (blockIdx.x >> 3);
  int by = swz / gn, bx = swz % gn;
  int m0 = by << 8, n0 = bx << 8;

  f32x4 acc[8][4] = {};
  short8_t ae[4][2], al[4][2], be[2][2], bl[2][2];

  int srcChunk = ((lane & 7) ^ (lane >> 3)) << 3;
  int rowInSlot = lane >> 3;
  const short* Ap = (const short*)A;
  const short* Bp = (const short*)Bt;

  auto stageA = [&](int bufI, int kkE, int late) {
#pragma unroll
    for (int i = 0; i < 2; ++i) {
      int idx = i * 8 + wv;
      int slot = ((idx >> 3) << 4) + (idx & 7) + (late ? 8 : 0);
      int row = slot * 8 + rowInSlot;
      gload16(Ap + (size_t)(m0 + row) * K + kkE + srcChunk, &As[bufI][slot << 9]);
    }
  };
  auto stageB = [&](int bufI, int kkE, int late) {
#pragma unroll
    for (int i = 0; i < 2; ++i) {
      int idx = i * 8 + wv;
      int slot = ((idx >> 2) << 3) + (idx & 3) + (late ? 4 : 0);
      int row = slot * 8 + rowInSlot;
      gload16(Bp + (size_t)(n0 + row) * K + kkE + srcChunk, &Bs[bufI][slot << 9]);
    }
  };

  int NT = K >> 6;
  stageA(0, 0, 0); stageB(0, 0, 0); stageA(0, 0, 1); stageB(0, 0, 1);
  stageA(1, 64, 0); stageB(1, 64, 0);
  VMCNT(4);
  BAR;

  for (int tt = 0; tt < NT; ++tt) {
    int buf = tt & 1;
    int k1 = ((tt + 1) < NT ? (tt + 1) : 0) << 6;
    int k2 = ((tt + 2) < NT ? (tt + 2) : 0) << 6;
    RDA(ae, buf, 0); RDB(be, buf, 0);
    stageA(buf ^ 1, k1, 1);
    BAR; SETPRIO(1); MMAQ(ae, be, 0, 0); SETPRIO(0);
    RDB(bl, buf, 1);
    BAR;
    stageB(buf ^ 1, k1, 1);
    BAR; SETPRIO(1); MMAQ(ae, bl, 0, 1); SETPRIO(0);
    RDA(al, buf, 1);
    BAR;
    stageA(buf, k2, 0);
    BAR; SETPRIO(1); MMAQ(al, bl, 1, 1); SETPRIO(0); BAR;
    stageB(buf, k2, 0);
    BAR; SETPRIO(1); MMAQ(al, be, 1, 0); SETPRIO(0);
    VMCNT(4);
    BAR;
  }
  VMCNT(0);

  int mo = m0 + wm * 128, no = n0 + wn * 64;
#pragma unroll
  for (int mf = 0; mf < 8; ++mf)
#pragma unroll
    for (int nf = 0; nf < 4; ++nf) {
      int n = no + nf * 16 + l15;
      float bia = bias[n];
#pragma unroll
      for (int r = 0; r < 4; ++r) {
        int m = mo + mf * 16 + koff * 4 + r;
        float vv = acc[mf][nf][r] + bia;
        size_t idx = (size_t)m * N + n;
        if (mode == 1) {
          ((short*)outB)[idx] = f2bf(vv);
        } else if (mode == 2) {
          float g = 0.5f * vv * (1.f + tanhf(0.7978845608f * (vv + 0.044715f * vv * vv * vv)));
          ((short*)outB)[idx] = f2bf(g);
        } else {
          float sc = scale ? scale[(size_t)(m / rows_per_b) * scstride + n] : 1.0f;
          outF[idx] = resid[idx] + vv * sc;
        }
      }
    }
}

// ---------------- 128x128 2-phase GEMM (proven R3) --------
__global__ __launch_bounds__(256) void gemm_bt(
    const bf16* __restrict__ A, const bf16* __restrict__ Bt,
    const float* __restrict__ bias,
    float* outF, bf16* outB,
    const float* resid, const float* __restrict__ scale,
    int scstride, int rows_per_b, int gn, int N, int K, int mode) {
  __shared__ short As[2][128 * 64];
  __shared__ short Bs[2][128 * 64];
  int t = threadIdx.x, lane = t & 63, wv = t >> 6;
  int nwg = gridDim.x, cpx = nwg >> 3;
  int swz = (blockIdx.x & 7) * cpx + (blockIdx.x >> 3);
  int by = swz / gn, bx = swz % gn;
  int m0 = by << 7, n0 = bx << 7;
  f32x4 acc[4][4] = {};
  int mo_l = (wv >> 1) << 6, no_l = (wv & 1) << 6;

  int srow[4], scol[4];
#pragma unroll
  for (int j = 0; j < 4; ++j) {
    srow[j] = wv * 32 + j * 8 + (lane >> 3);
    scol[j] = ((lane & 7) ^ (srow[j] & 7)) << 3;
  }
  const short* Ap = (const short*)A;
  const short* Bp = (const short*)Bt;

  int koff = lane >> 4;
  int rowA[4], rowB[4];
#pragma unroll
  for (int i = 0; i < 4; ++i) {
    rowA[i] = mo_l + i * 16 + (lane & 15);
    rowB[i] = no_l + i * 16 + (lane & 15);
  }

  auto stage = [&](int bufI, int kk) {
#pragma unroll
    for (int j = 0; j < 4; ++j) {
      gload16(Ap + (size_t)(m0 + srow[j]) * K + kk + scol[j],
              &As[bufI][(wv * 32 + j * 8) * 64]);
      gload16(Bp + (size_t)(n0 + srow[j]) * K + kk + scol[j],
              &Bs[bufI][(wv * 32 + j * 8) * 64]);
    }
  };

  stage(0, 0);
  __syncthreads();
  int cur = 0;
  for (int kk = 0; kk < K; kk += 64) {
    int nxt = cur ^ 1;
    if (kk + 64 < K) stage(nxt, kk + 64);
    short8_t af[2][4], bfv[2][4];
#pragma unroll
    for (int h = 0; h < 2; ++h)
#pragma unroll
      for (int i = 0; i < 4; ++i) {
        int cA = ((h * 4 + koff) ^ (rowA[i] & 7)) << 3;
        af[h][i] = *(const short8_t*)&As[cur][rowA[i] * 64 + cA];
        int cB = ((h * 4 + koff) ^ (rowB[i] & 7)) << 3;
        bfv[h][i] = *(const short8_t*)&Bs[cur][rowB[i] * 64 + cB];
      }
#pragma unroll
    for (int h = 0; h < 2; ++h)
#pragma unroll
      for (int mt = 0; mt < 4; ++mt)
#pragma unroll
        for (int nt = 0; nt < 4; ++nt)
          acc[mt][nt] = __builtin_amdgcn_mfma_f32_16x16x32_bf16(af[h][mt], bfv[h][nt], acc[mt][nt], 0, 0, 0);
    __syncthreads();
    cur = nxt;
  }

  int mo = m0 + mo_l, no = n0 + no_l;
#pragma unroll
  for (int mt = 0; mt < 4; ++mt)
#pragma unroll
    for (int nt = 0; nt < 4; ++nt) {
      int n = no + nt * 16 + (lane & 15);
      float bia = bias[n];
#pragma unroll
      for (int r = 0; r < 4; ++r) {
        int m = mo + mt * 16 + (lane >> 4) * 4 + r;
        float vv = acc[mt][nt][r] + bia;
        size_t idx = (size_t)m * N + n;
        if (mode == 1) {
          ((short*)outB)[idx] = f2bf(vv);
        } else if (mode == 2) {
          float g = 0.5f * vv * (1.f + tanhf(0.7978845608f * (vv + 0.044715f * vv * vv * vv)));
          ((short*)outB)[idx] = f2bf(g);
        } else {
          float sc = scale ? scale[(size_t)(m / rows_per_b) * scstride + n] : 1.0f;
          outF[idx] = resid[idx] + vv * sc;
        }
      }
    }
}

// Flash attention v2: kv-XOR-swizzled V^T (conflict fix), packed-dword P path,
// log2-domain online softmax.  Same structure as passing R6 otherwise.
__global__ __launch_bounds__(256) void attn_kernel(
    const bf16* __restrict__ q, const bf16* __restrict__ k,
    const bf16* __restrict__ v, bf16* __restrict__ y,
    int QL, int KVL, int qs, int ks, int vs, float scl) {
  __shared__ short Kt[64 * 136];
  __shared__ short Vt[128 * 72];
  __shared__ unsigned Pl[64 * 36];
  __shared__ float rl[4 * 16];
  __shared__ float ll[4 * 16];
  int t = threadIdx.x, lane = t & 63, wv = t >> 6;
  int l15 = lane & 15, koff = lane >> 4;
  int bh = blockIdx.y;
  int b = bh / NHEADS, h = bh % NHEADS;
  int q0 = blockIdx.x * 64 + wv * 16;
  const short* qp = (const short*)q;
  const short* kp = (const short*)k;
  const short* vp = (const short*)v;
  const float c1 = scl * 1.44269504088896f;  // scl * log2(e)
  short8_t qf[4];
  {
    size_t qbase = ((size_t)(b * QL) + q0 + l15) * qs + h * HDIM + koff * 8;
#pragma unroll
    for (int kc = 0; kc < 4; ++kc) qf[kc] = *(const short8_t*)(qp + qbase + kc * 32);
  }
  f32x4 o[8] = {};
  float m_run = -1e30f, l_run = 0.f;
  int strow = t >> 2, stcol = (t & 3) * 32;
  for (int kt0 = 0; kt0 < KVL; kt0 += 64) {
    const short* ksrc = kp + ((size_t)(b * KVL + kt0 + strow) * ks + h * HDIM + stcol);
    const short* vsrc = vp + ((size_t)(b * KVL + kt0 + strow) * vs + h * HDIM + stcol);
#pragma unroll
    for (int c = 0; c < 4; ++c)
      *(short8_t*)&Kt[strow * 136 + stcol + c * 8] = *(const short8_t*)(ksrc + c * 8);
#pragma unroll
    for (int c = 0; c < 4; ++c) {
      short8_t vvv = *(const short8_t*)(vsrc + c * 8);
#pragma unroll
      for (int e = 0; e < 8; ++e) {
        int d = stcol + c * 8 + e;
        Vt[d * 72 + (strow ^ ((d >> 2) & 0x38))] = vvv[e];
      }
    }
    __syncthreads();
    f32x4 st[4];
#pragma unroll
    for (int kt = 0; kt < 4; ++kt) {
      f32x4 aa = {0.f, 0.f, 0.f, 0.f};
#pragma unroll
      for (int kc = 0; kc < 4; ++kc) {
        short8_t kf = *(const short8_t*)&Kt[(kt * 16 + l15) * 136 + kc * 32 + koff * 8];
        aa = __builtin_amdgcn_mfma_f32_16x16x32_bf16(kf, qf[kc], aa, 0, 0, 0);
      }
      st[kt] = aa;
    }
    float mt_ = -1e30f;
#pragma unroll
    for (int kt = 0; kt < 4; ++kt)
#pragma unroll
      for (int r = 0; r < 4; ++r) mt_ = fmaxf(mt_, st[kt][r]);
    mt_ = fmaxf(mt_, __shfl_xor(mt_, 16, 64));
    mt_ = fmaxf(mt_, __shfl_xor(mt_, 32, 64));
    float m_new = fmaxf(m_run, mt_ * c1);
    float rfac = exp2f(m_run - m_new);
    float ps = 0.f;
#pragma unroll
    for (int kt = 0; kt < 4; ++kt)
#pragma unroll
      for (int r = 0; r < 4; ++r) {
        float p = exp2f(fmaf(st[kt][r], c1, -m_new));
        st[kt][r] = p;
        ps += p;
      }
    ps += __shfl_xor(ps, 16, 64);
    ps += __shfl_xor(ps, 32, 64);
    l_run = l_run * rfac + ps;
    m_run = m_new;
    if (lane < 16) rl[wv * 16 + lane] = rfac;
    // pack P to bf16 dwords: Pl[q][kd], kd = kt*8 + koff*2 + rp
#pragma unroll
    for (int kt = 0; kt < 4; ++kt)
#pragma unroll
      for (int rp = 0; rp < 2; ++rp) {
        unsigned lo = (unsigned short)f2bf(st[kt][2 * rp]);
        unsigned hi = (unsigned short)f2bf(st[kt][2 * rp + 1]);
        Pl[(wv * 16 + l15) * 36 + kt * 8 + koff * 2 + rp] = lo | (hi << 16);
      }
    float rr[4];
#pragma unroll
    for (int r = 0; r < 4; ++r) rr[r] = rl[wv * 16 + koff * 4 + r];
#pragma unroll
    for (int dt = 0; dt < 8; ++dt)
#pragma unroll
      for (int r = 0; r < 4; ++r) o[dt][r] *= rr[r];
#pragma unroll
    for (int kc2 = 0; kc2 < 2; ++kc2) {
      short8_t pa = *(const short8_t*)&Pl[(wv * 16 + l15) * 36 + kc2 * 16 + koff * 4];
#pragma unroll
      for (int dt = 0; dt < 8; ++dt) {
        int drow = dt * 16 + l15;
        int kv0 = (kc2 * 32 + koff * 8) ^ ((drow >> 2) & 0x38);
        short8_t vf = *(const short8_t*)&Vt[drow * 72 + kv0];
        o[dt] = __builtin_amdgcn_mfma_f32_16x16x32_bf16(pa, vf, o[dt], 0, 0, 0);
      }
    }
    __syncthreads();
  }
  if (lane < 16) ll[wv * 16 + lane] = 1.f / l_run;
  float li[4];
#pragma unroll
  for (int r = 0; r < 4; ++r) li[r] = ll[wv * 16 + koff * 4 + r];
  short* yp = (short*)y;
#pragma unroll
  for (int dt = 0; dt < 8; ++dt)
#pragma unroll
    for (int r = 0; r < 4; ++r) {
      int qq = q0 + koff * 4 + r;
      int d = dt * 16 + l15;
      yp[((size_t)(b * QL) + qq) * DIMX + h * HDIM + d] = f2bf(o[dt][r] * li[r]);
    }
}

// ws layout (bytes)
#define OFF_EM    0ull
#define OFF_BQKV  (512ull << 10)
#define OFF_BCKV  (560ull << 10)
#define OFF_XN    (1ull << 20)
#define OFF_QKV   (17ull << 20)
#define OFF_CAQ   (17ull << 20)
#define OFF_KV    (33ull << 20)
#define OFF_QB    (65ull << 20)
#define OFF_KB    (81ull << 20)
#define OFF_YB    (97ull << 20)
#define OFF_CTX   (113ull << 20)
#define OFF_WBUF  (117ull << 20)
#define OFF_HB    (17ull << 20)

extern "C" void kernel_launch(void* const* d_in, const int* in_sizes, int n_in,
                              void* d_out, int out_size, void* d_ws, size_t ws_size,
                              hipStream_t stream) {
  const float* x       = (const float*)d_in[0];
  const float* e       = (const float*)d_in[1];
  const float* context = (const float*)d_in[2];
  const float* fcos    = (const float*)d_in[3];
  const float* fsin    = (const float*)d_in[4];
  const float* modu    = (const float*)d_in[5];
  const float* sa_wq = (const float*)d_in[6];  const float* sa_bq = (const float*)d_in[7];
  const float* sa_wk = (const float*)d_in[8];  const float* sa_bk = (const float*)d_in[9];
  const float* sa_wv = (const float*)d_in[10]; const float* sa_bv = (const float*)d_in[11];
  const float* sa_wo = (const float*)d_in[12]; const float* sa_bo = (const float*)d_in[13];
  const float* sa_nq = (const float*)d_in[14]; const float* sa_nk = (const float*)d_in[15];
  const float* ca_wq = (const float*)d_in[16]; const float* ca_bq = (const float*)d_in[17];
  const float* ca_wk = (const float*)d_in[18]; const float* ca_bk = (const float*)d_in[19];
  const float* ca_wv = (const float*)d_in[20]; const float* ca_bv = (const float*)d_in[21];
  const float* ca_wo = (const float*)d_in[22]; const float* ca_bo = (const float*)d_in[23];
  const float* ca_nq = (const float*)d_in[24]; const float* ca_nk = (const float*)d_in[25];
  const float* n3_w  = (const float*)d_in[26]; const float* n3_b  = (const float*)d_in[27];
  const float* f_w1  = (const float*)d_in[28]; const float* f_b1  = (const float*)d_in[29];
  const float* f_w2  = (const float*)d_in[30]; const float* f_b2  = (const float*)d_in[31];

  char* ws = (char*)d_ws;
  float* em   = (float*)(ws + OFF_EM);
  float* bqkv = (float*)(ws + OFF_BQKV);
  float* bckv = (float*)(ws + OFF_BCKV);
  bf16* xn    = (bf16*)(ws + OFF_XN);
  bf16* qkvb  = (bf16*)(ws + OFF_QKV);
  bf16* caqb  = (bf16*)(ws + OFF_CAQ);
  bf16* kvb   = (bf16*)(ws + OFF_KV);
  bf16* qb    = (bf16*)(ws + OFF_QB);
  bf16* kb    = (bf16*)(ws + OFF_KB);
  bf16* yb    = (bf16*)(ws + OFF_YB);
  bf16* ctxb  = (bf16*)(ws + OFF_CTX);
  bf16* wbuf  = (bf16*)(ws + OFF_WBUF);
  bf16* hb    = (bf16*)(ws + OFF_HB);
  float* xw   = (float*)d_out;

  const int M = BSZ * SLEN;
  const int MC = BSZ * CTXL;
  const float scl = 0.08838834764831845f;

#define TRANSO(W, Kd, Nd, noff) \
  transpose_w<<<dim3((Nd) / 64, (Kd) / 64), 256, 0, stream>>>(W, wbuf, Kd, Nd, noff)
#define GEMM256(Am, Md, Nd, Kd, bias, oF, oB, res, sc, scs, rpb, mode) \
  gemm256<<<((Md) / 256) * ((Nd) / 256), 512, 0, stream>>>(Am, wbuf, bias, oF, oB, res, sc, \
                                                           scs, rpb, (Nd) / 256, Nd, Kd, mode)
#define GEMM128(Am, Md, Nd, Kd, bias, oF, oB, res, sc, scs, rpb, mode) \
  gemm_bt<<<((Md) / 128) * ((Nd) / 128), 256, 0, stream>>>(Am, wbuf, bias, oF, oB, res, sc, scs, rpb, (Nd) / 128, Nd, Kd, mode)

  em_kernel<<<(BSZ * 6 * DIMX + 255) / 256, 256, 0, stream>>>(e, modu, em, BSZ * 6 * DIMX);
  cvt_kernel<<<(MC * DIMX / 8 + 255) / 256, 256, 0, stream>>>(context, ctxb, MC * DIMX / 8);
  packb_kernel<<<(3 * DIMX + 255) / 256, 256, 0, stream>>>(sa_bq, sa_bk, sa_bv, bqkv, 3 * DIMX);
  packb_kernel<<<(2 * DIMX + 255) / 256, 256, 0, stream>>>(ca_bk, ca_bv, nullptr, bckv, 2 * DIMX);

  // --- self attention ---
  ln_kernel<<<M, 256, 0, stream>>>(x, em + 1 * DIMX, em + 0 * DIMX, 6 * DIMX, 1.0f, SLEN, xn);

  TRANSO(sa_wq, DIMX, DIMX, 0);
  TRANSO(sa_wk, DIMX, DIMX, DIMX);
  TRANSO(sa_wv, DIMX, DIMX, 2 * DIMX);
  GEMM256(xn, M, 3 * DIMX, DIMX, bqkv, nullptr, qkvb, nullptr, nullptr, 0, 1, 1);
  rms_rope_kernel<<<M, 256, 0, stream>>>(qkvb, 3 * DIMX, sa_nq, fcos, fsin, 1, qb);
  rms_rope_kernel<<<M, 256, 0, stream>>>((bf16*)((short*)qkvb + DIMX), 3 * DIMX, sa_nk, fcos, fsin, 1, kb);

  attn_kernel<<<dim3(SLEN / 64, BSZ * NHEADS), 256, 0, stream>>>(
      qb, kb, (bf16*)((short*)qkvb + 2 * DIMX), yb, SLEN, SLEN, DIMX, DIMX, 3 * DIMX, scl);

  TRANSO(sa_wo, DIMX, DIMX, 0);
  GEMM128(yb, M, DIMX, DIMX, sa_bo, xw, nullptr, x, em + 2 * DIMX, 6 * DIMX, SLEN, 3);

  // --- cross attention ---
  ln_kernel<<<M, 256, 0, stream>>>(xw, n3_w, n3_b, 0, 0.0f, SLEN, xn);

  TRANSO(ca_wq, DIMX, DIMX, 0);
  GEMM128(xn, M, DIMX, DIMX, ca_bq, nullptr, caqb, nullptr, nullptr, 0, 1, 1);
  rms_rope_kernel<<<M, 256, 0, stream>>>(caqb, DIMX, ca_nq, fcos, fsin, 0, qb);

  TRANSO(ca_wk, DIMX, DIMX, 0);
  TRANSO(ca_wv, DIMX, DIMX, DIMX);
  GEMM128(ctxb, MC, 2 * DIMX, DIMX, bckv, nullptr, kvb, nullptr, nullptr, 0, 1, 1);
  rms_rope_kernel<<<MC, 256, 0, stream>>>(kvb, 2 * DIMX, ca_nk, fcos, fsin, 0, kb);

  attn_kernel<<<dim3(SLEN / 64, BSZ * NHEADS), 256, 0, stream>>>(
      qb, kb, (bf16*)((short*)kvb + DIMX), yb, SLEN, CTXL, DIMX, DIMX, 2 * DIMX, scl);

  TRANSO(ca_wo, DIMX, DIMX, 0);
  GEMM128(yb, M, DIMX, DIMX, ca_bo, xw, nullptr, xw, nullptr, 0, SLEN, 3);

  // --- FFN ---
  ln_kernel<<<M, 256, 0, stream>>>(xw, em + 4 * DIMX, em + 3 * DIMX, 6 * DIMX, 1.0f, SLEN, xn);

  TRANSO(f_w1, DIMX, FFND, 0);
  GEMM256(xn, M, FFND, DIMX, f_b1, nullptr, hb, nullptr, nullptr, 0, 1, 2);

  TRANSO(f_w2, FFND, DIMX, 0);
  GEMM128(hb, M, DIMX, FFND, f_b2, xw, nullptr, xw, em + 5 * DIMX, 6 * DIMX, SLEN, 3);
}